// Round 1
// baseline (126.943 us; speedup 1.0000x reference)
//
#include <hip/hip_runtime.h>
#include <math.h>

#define T 1024
#define NB 64

__device__ __forceinline__ float clip01(float v) {
    return fminf(fmaxf(v, 0.0f), 1.0f);
}

// ---------------------------------------------------------------------------
// Kernel 1: softmax each of the six length-T vectors (A1_1,A2_1,A1_2,A2_2,
// A1_3,A2_3) into ws[blockIdx.x*T ...]. 6 blocks x 256 threads, 4 elems/thread.
// ---------------------------------------------------------------------------
__global__ __launch_bounds__(256) void k_softmax6(
    const float* __restrict__ p0, const float* __restrict__ p1,
    const float* __restrict__ p2, const float* __restrict__ p3,
    const float* __restrict__ p4, const float* __restrict__ p5,
    float* __restrict__ ws)
{
    __shared__ float red[256];
    const float* src;
    switch (blockIdx.x) {
        case 0:  src = p0; break;
        case 1:  src = p1; break;
        case 2:  src = p2; break;
        case 3:  src = p3; break;
        case 4:  src = p4; break;
        default: src = p5; break;
    }
    float* dst = ws + (size_t)blockIdx.x * T;
    int tid = threadIdx.x;

    float4 v = ((const float4*)src)[tid];
    float m = fmaxf(fmaxf(v.x, v.y), fmaxf(v.z, v.w));
    red[tid] = m;
    __syncthreads();
    for (int s = 128; s > 0; s >>= 1) {
        if (tid < s) red[tid] = fmaxf(red[tid], red[tid + s]);
        __syncthreads();
    }
    float bmax = red[0];
    __syncthreads();

    float e0 = expf(v.x - bmax), e1 = expf(v.y - bmax);
    float e2 = expf(v.z - bmax), e3 = expf(v.w - bmax);
    red[tid] = (e0 + e1) + (e2 + e3);
    __syncthreads();
    for (int s = 128; s > 0; s >>= 1) {
        if (tid < s) red[tid] += red[tid + s];
        __syncthreads();
    }
    float inv = 1.0f / red[0];
    ((float4*)dst)[tid] = make_float4(e0 * inv, e1 * inv, e2 * inv, e3 * inv);
}

// ---------------------------------------------------------------------------
// Kernel 2: one block per (branch, batch). 192 blocks x 256 threads.
// Computes S_ext[2T] in LDS (S_ext[k<T] = sigmoid(b - x[k]*t) with the
// r==b -> -10 special case; S_ext[k>=T] = sigmoid(-10)), then each thread
// computes 4 consecutive rows of the correlation with a sliding register
// window, applies clip + A2-weighted reduction, and writes wb2 for its batch.
// ---------------------------------------------------------------------------
__global__ __launch_bounds__(256) void k_branch_all(
    const float* __restrict__ x1, const float* __restrict__ x2,
    const float* __restrict__ x3,
    const float* __restrict__ t1p, const float* __restrict__ b1p,
    const float* __restrict__ ba1, const float* __restrict__ bb1,
    const float* __restrict__ t2p, const float* __restrict__ b2p,
    const float* __restrict__ ba2, const float* __restrict__ bb2,
    const float* __restrict__ t3p, const float* __restrict__ b3p,
    const float* __restrict__ ba3, const float* __restrict__ bb3,
    const float* __restrict__ ws, float* __restrict__ rws)
{
    __shared__ float sS[2 * T];   // 8 KB: S extended with sigmoid(-10) tail
    __shared__ float red[256];

    const int br    = blockIdx.x >> 6;   // 0..2
    const int batch = blockIdx.x & 63;   // 0..63
    const int tid   = threadIdx.x;

    const float *x, *tp, *bp, *bap, *bbp;
    if (br == 0)      { x = x1; tp = t1p; bp = b1p; bap = ba1; bbp = bb1; }
    else if (br == 1) { x = x2; tp = t2p; bp = b2p; bap = ba2; bbp = bb2; }
    else              { x = x3; tp = t3p; bp = b3p; bap = ba3; bbp = bb3; }

    const float* __restrict__ A1p = ws + (size_t)(2 * br) * T;       // A1sm
    const float* __restrict__ A2p = ws + (size_t)(2 * br + 1) * T;   // A2sm

    const float tt = *tp;
    const float bb = *bp;
    const float beta_a = *bap;
    const float beta_b = *bbp;
    const float sig10 = 1.0f / (1.0f + expf(10.0f));   // sigmoid(-10)

    // --- stage S_ext into LDS ---
    const float* xrow = x + (size_t)batch * T;
    float4 xv = ((const float4*)xrow)[tid];
    float4 sv;
    {
        float p, r;
        p = __fmul_rn(xv.x, tt); r = __fsub_rn(bb, p); if (r == bb) r = -10.0f;
        sv.x = 1.0f / (1.0f + expf(-r));
        p = __fmul_rn(xv.y, tt); r = __fsub_rn(bb, p); if (r == bb) r = -10.0f;
        sv.y = 1.0f / (1.0f + expf(-r));
        p = __fmul_rn(xv.z, tt); r = __fsub_rn(bb, p); if (r == bb) r = -10.0f;
        sv.z = 1.0f / (1.0f + expf(-r));
        p = __fmul_rn(xv.w, tt); r = __fsub_rn(bb, p); if (r == bb) r = -10.0f;
        sv.w = 1.0f / (1.0f + expf(-r));
    }
    ((float4*)sS)[tid] = sv;
    ((float4*)(sS + T))[tid] = make_float4(sig10, sig10, sig10, sig10);
    __syncthreads();

    // --- correlation: rows i0..i0+3, sliding window over S_ext ---
    const int i0 = tid << 2;
    float acc0 = 0.0f, acc1 = 0.0f, acc2 = 0.0f, acc3 = 0.0f;
    float4 u = *(const float4*)&sS[i0];
    #pragma unroll 4
    for (int j = 0; j < T; j += 4) {
        float4 a = *(const float4*)&A1p[j];          // block-uniform -> s_load
        float4 v = *(const float4*)&sS[i0 + j + 4];  // 1 new float4 per step
        acc0 = fmaf(a.x, u.x, acc0); acc0 = fmaf(a.y, u.y, acc0);
        acc0 = fmaf(a.z, u.z, acc0); acc0 = fmaf(a.w, u.w, acc0);
        acc1 = fmaf(a.x, u.y, acc1); acc1 = fmaf(a.y, u.z, acc1);
        acc1 = fmaf(a.z, u.w, acc1); acc1 = fmaf(a.w, v.x, acc1);
        acc2 = fmaf(a.x, u.z, acc2); acc2 = fmaf(a.y, u.w, acc2);
        acc2 = fmaf(a.z, v.x, acc2); acc2 = fmaf(a.w, v.y, acc2);
        acc3 = fmaf(a.x, u.w, acc3); acc3 = fmaf(a.y, v.x, acc3);
        acc3 = fmaf(a.z, v.y, acc3); acc3 = fmaf(a.w, v.z, acc3);
        u = v;
    }

    // --- epilogue: wb1 -> act1 -> A2-weighted partial sum ---
    float act0 = clip01(1.0f - beta_a + acc0);
    float act1 = clip01(1.0f - beta_a + acc1);
    float act2 = clip01(1.0f - beta_a + acc2);
    float act3 = clip01(1.0f - beta_a + acc3);

    float4 a2 = ((const float4*)A2p)[tid];
    float part = a2.x * (1.0f - act0) + a2.y * (1.0f - act1)
               + a2.z * (1.0f - act2) + a2.w * (1.0f - act3);

    red[tid] = part;
    __syncthreads();
    for (int s = 128; s > 0; s >>= 1) {
        if (tid < s) red[tid] += red[tid + s];
        __syncthreads();
    }
    if (tid == 0) {
        rws[br * NB + batch] = clip01(beta_b - red[0]);
    }
}

// ---------------------------------------------------------------------------
// Kernel 3: final 3-way softmax combine. 1 block x 64 threads.
// ---------------------------------------------------------------------------
__global__ __launch_bounds__(64) void k_final(
    const float* __restrict__ A4, const float* __restrict__ beta4p,
    const float* __restrict__ rws, float* __restrict__ out)
{
    int b = threadIdx.x;
    float a0 = A4[0], a1 = A4[1], a2 = A4[2];
    float m = fmaxf(a0, fmaxf(a1, a2));
    float e0 = expf(a0 - m), e1 = expf(a1 - m), e2 = expf(a2 - m);
    float inv = 1.0f / ((e0 + e1) + e2);
    float beta4 = *beta4p;
    float r0 = rws[0 * NB + b];
    float r1 = rws[1 * NB + b];
    float r2 = rws[2 * NB + b];
    float wb4 = beta4 - (e0 * inv * (1.0f - r0)
                       + e1 * inv * (1.0f - r1)
                       + e2 * inv * (1.0f - r2));
    out[b] = clip01(wb4);
}

extern "C" void kernel_launch(void* const* d_in, const int* in_sizes, int n_in,
                              void* d_out, int out_size, void* d_ws, size_t ws_size,
                              hipStream_t stream) {
    const float* x1    = (const float*)d_in[0];
    const float* x2    = (const float*)d_in[1];
    const float* x3    = (const float*)d_in[2];
    const float* t1    = (const float*)d_in[3];
    const float* b1    = (const float*)d_in[4];
    const float* A1_1  = (const float*)d_in[5];
    const float* A2_1  = (const float*)d_in[6];
    const float* be1a  = (const float*)d_in[7];
    const float* be1b  = (const float*)d_in[8];
    const float* t2    = (const float*)d_in[9];
    const float* b2    = (const float*)d_in[10];
    const float* A1_2  = (const float*)d_in[11];
    const float* A2_2  = (const float*)d_in[12];
    const float* be2a  = (const float*)d_in[13];
    const float* be2b  = (const float*)d_in[14];
    const float* t3    = (const float*)d_in[15];
    const float* b3    = (const float*)d_in[16];
    const float* A1_3  = (const float*)d_in[17];
    const float* A2_3  = (const float*)d_in[18];
    const float* be3a  = (const float*)d_in[19];
    const float* be3b  = (const float*)d_in[20];
    const float* A4    = (const float*)d_in[21];
    const float* beta4 = (const float*)d_in[22];

    float* ws  = (float*)d_ws;          // 6*T floats: softmaxed A vectors
    float* rws = ws + 6 * T;            // 3*64 floats: per-branch wb2

    // order in ws: [A1sm_1, A2sm_1, A1sm_2, A2sm_2, A1sm_3, A2sm_3]
    k_softmax6<<<6, 256, 0, stream>>>(A1_1, A2_1, A1_2, A2_2, A1_3, A2_3, ws);

    k_branch_all<<<192, 256, 0, stream>>>(
        x1, x2, x3,
        t1, b1, be1a, be1b,
        t2, b2, be2a, be2b,
        t3, b3, be3a, be3b,
        ws, rws);

    k_final<<<1, 64, 0, stream>>>(A4, beta4, rws, (float*)d_out);
}

// Round 2
// 126.581 us; speedup vs baseline: 1.0029x; 1.0029x over previous
//
#include <hip/hip_runtime.h>
#include <math.h>

#define T 1024
#define NB 64

__device__ __forceinline__ float clip01(float v) {
    return fminf(fmaxf(v, 0.0f), 1.0f);
}

__device__ __forceinline__ float wave_reduce_sum(float v) {
    #pragma unroll
    for (int off = 32; off > 0; off >>= 1) v += __shfl_xor(v, off, 64);
    return v;
}

__device__ __forceinline__ float wave_reduce_max(float v) {
    #pragma unroll
    for (int off = 32; off > 0; off >>= 1) v = fmaxf(v, __shfl_xor(v, off, 64));
    return v;
}

// ---------------------------------------------------------------------------
// Kernel 1: softmax each of the six length-T vectors into ws.
// 6 blocks x 256 threads, shuffle-based reductions (2 barriers total).
// ---------------------------------------------------------------------------
__global__ __launch_bounds__(256) void k_softmax6(
    const float* __restrict__ p0, const float* __restrict__ p1,
    const float* __restrict__ p2, const float* __restrict__ p3,
    const float* __restrict__ p4, const float* __restrict__ p5,
    float* __restrict__ ws)
{
    __shared__ float pm[4];
    __shared__ float ps[4];
    const float* src;
    switch (blockIdx.x) {
        case 0:  src = p0; break;
        case 1:  src = p1; break;
        case 2:  src = p2; break;
        case 3:  src = p3; break;
        case 4:  src = p4; break;
        default: src = p5; break;
    }
    float* dst = ws + (size_t)blockIdx.x * T;
    const int tid  = threadIdx.x;
    const int wave = tid >> 6;
    const int lane = tid & 63;

    float4 v = ((const float4*)src)[tid];
    float m = fmaxf(fmaxf(v.x, v.y), fmaxf(v.z, v.w));
    m = wave_reduce_max(m);
    if (lane == 0) pm[wave] = m;
    __syncthreads();
    float bmax = fmaxf(fmaxf(pm[0], pm[1]), fmaxf(pm[2], pm[3]));

    float e0 = expf(v.x - bmax), e1 = expf(v.y - bmax);
    float e2 = expf(v.z - bmax), e3 = expf(v.w - bmax);
    float s = (e0 + e1) + (e2 + e3);
    s = wave_reduce_sum(s);
    if (lane == 0) ps[wave] = s;
    __syncthreads();
    float inv = 1.0f / ((ps[0] + ps[1]) + (ps[2] + ps[3]));
    ((float4*)dst)[tid] = make_float4(e0 * inv, e1 * inv, e2 * inv, e3 * inv);
}

// ---------------------------------------------------------------------------
// Kernel 2: one block per (branch, batch) = 192 blocks x 256 threads.
// S_ext[2T] in LDS; A1sm read from GLOBAL with a block-uniform index so the
// compiler can put it on the scalar pipe (s_load_dwordx4) and keep the LDS
// unit free for the sliding-window reads. unroll 8 => 8 window loads +
// 8 A-loads in flight, hiding ~120cyc LDS latency at 1 wave/SIMD.
// ---------------------------------------------------------------------------
__global__ __launch_bounds__(256, 1) void k_branch_all(
    const float* __restrict__ x1, const float* __restrict__ x2,
    const float* __restrict__ x3,
    const float* __restrict__ t1p, const float* __restrict__ b1p,
    const float* __restrict__ ba1, const float* __restrict__ bb1,
    const float* __restrict__ t2p, const float* __restrict__ b2p,
    const float* __restrict__ ba2, const float* __restrict__ bb2,
    const float* __restrict__ t3p, const float* __restrict__ b3p,
    const float* __restrict__ ba3, const float* __restrict__ bb3,
    const float* __restrict__ ws, float* __restrict__ rws)
{
    __shared__ float sS[2 * T];   // 8 KB
    __shared__ float psum[4];

    const int br    = blockIdx.x >> 6;   // 0..2
    const int batch = blockIdx.x & 63;   // 0..63
    const int tid   = threadIdx.x;
    const int wave  = tid >> 6;
    const int lane  = tid & 63;

    const float *x, *tp, *bp, *bap, *bbp;
    if (br == 0)      { x = x1; tp = t1p; bp = b1p; bap = ba1; bbp = bb1; }
    else if (br == 1) { x = x2; tp = t2p; bp = b2p; bap = ba2; bbp = bb2; }
    else              { x = x3; tp = t3p; bp = b3p; bap = ba3; bbp = bb3; }

    const float4* __restrict__ A1v = (const float4*)(ws + (size_t)(2 * br) * T);
    const float4* __restrict__ A2v = (const float4*)(ws + (size_t)(2 * br + 1) * T);

    // Issue all global loads up front.
    const float4 xv = ((const float4*)(x + (size_t)batch * T))[tid];
    const float4 a2 = A2v[tid];
    const float tt = *tp;
    const float bb = *bp;
    const float beta_a = *bap;
    const float beta_b = *bbp;
    const float sig10 = 1.0f / (1.0f + expf(10.0f));   // sigmoid(-10)

    // --- stage S_ext into LDS (exact mul/sub semantics for the r==b test) ---
    float4 sv;
    {
        float p, r;
        p = __fmul_rn(xv.x, tt); r = __fsub_rn(bb, p); if (r == bb) r = -10.0f;
        sv.x = 1.0f / (1.0f + expf(-r));
        p = __fmul_rn(xv.y, tt); r = __fsub_rn(bb, p); if (r == bb) r = -10.0f;
        sv.y = 1.0f / (1.0f + expf(-r));
        p = __fmul_rn(xv.z, tt); r = __fsub_rn(bb, p); if (r == bb) r = -10.0f;
        sv.z = 1.0f / (1.0f + expf(-r));
        p = __fmul_rn(xv.w, tt); r = __fsub_rn(bb, p); if (r == bb) r = -10.0f;
        sv.w = 1.0f / (1.0f + expf(-r));
    }
    ((float4*)sS)[tid] = sv;
    ((float4*)(sS + T))[tid] = make_float4(sig10, sig10, sig10, sig10);
    __syncthreads();

    // --- correlation: rows 4*tid .. 4*tid+3, sliding register window ---
    float acc0 = 0.0f, acc1 = 0.0f, acc2 = 0.0f, acc3 = 0.0f;
    float4 u = ((const float4*)sS)[tid];
    #pragma unroll 8
    for (int jv = 0; jv < T / 4; ++jv) {
        const float4 a = A1v[jv];                     // block-uniform -> scalar pipe
        const float4 v = ((const float4*)sS)[tid + jv + 1];
        acc0 = fmaf(a.x, u.x, acc0); acc0 = fmaf(a.y, u.y, acc0);
        acc0 = fmaf(a.z, u.z, acc0); acc0 = fmaf(a.w, u.w, acc0);
        acc1 = fmaf(a.x, u.y, acc1); acc1 = fmaf(a.y, u.z, acc1);
        acc1 = fmaf(a.z, u.w, acc1); acc1 = fmaf(a.w, v.x, acc1);
        acc2 = fmaf(a.x, u.z, acc2); acc2 = fmaf(a.y, u.w, acc2);
        acc2 = fmaf(a.z, v.x, acc2); acc2 = fmaf(a.w, v.y, acc2);
        acc3 = fmaf(a.x, u.w, acc3); acc3 = fmaf(a.y, v.x, acc3);
        acc3 = fmaf(a.z, v.y, acc3); acc3 = fmaf(a.w, v.z, acc3);
        u = v;
    }

    // --- epilogue: wb1 -> act -> A2-weighted partial, shuffle reduce ---
    float act0 = clip01(1.0f - beta_a + acc0);
    float act1 = clip01(1.0f - beta_a + acc1);
    float act2 = clip01(1.0f - beta_a + acc2);
    float act3 = clip01(1.0f - beta_a + acc3);

    float part = a2.x * (1.0f - act0) + a2.y * (1.0f - act1)
               + a2.z * (1.0f - act2) + a2.w * (1.0f - act3);
    part = wave_reduce_sum(part);
    if (lane == 0) psum[wave] = part;
    __syncthreads();
    if (tid == 0) {
        float tot = (psum[0] + psum[1]) + (psum[2] + psum[3]);
        rws[br * NB + batch] = clip01(beta_b - tot);
    }
}

// ---------------------------------------------------------------------------
// Kernel 3: final 3-way softmax combine. 1 block x 64 threads.
// ---------------------------------------------------------------------------
__global__ __launch_bounds__(64) void k_final(
    const float* __restrict__ A4, const float* __restrict__ beta4p,
    const float* __restrict__ rws, float* __restrict__ out)
{
    int b = threadIdx.x;
    float a0 = A4[0], a1 = A4[1], a2 = A4[2];
    float m = fmaxf(a0, fmaxf(a1, a2));
    float e0 = expf(a0 - m), e1 = expf(a1 - m), e2 = expf(a2 - m);
    float inv = 1.0f / ((e0 + e1) + e2);
    float beta4 = *beta4p;
    float r0 = rws[0 * NB + b];
    float r1 = rws[1 * NB + b];
    float r2 = rws[2 * NB + b];
    float wb4 = beta4 - (e0 * inv * (1.0f - r0)
                       + e1 * inv * (1.0f - r1)
                       + e2 * inv * (1.0f - r2));
    out[b] = clip01(wb4);
}

extern "C" void kernel_launch(void* const* d_in, const int* in_sizes, int n_in,
                              void* d_out, int out_size, void* d_ws, size_t ws_size,
                              hipStream_t stream) {
    const float* x1    = (const float*)d_in[0];
    const float* x2    = (const float*)d_in[1];
    const float* x3    = (const float*)d_in[2];
    const float* t1    = (const float*)d_in[3];
    const float* b1    = (const float*)d_in[4];
    const float* A1_1  = (const float*)d_in[5];
    const float* A2_1  = (const float*)d_in[6];
    const float* be1a  = (const float*)d_in[7];
    const float* be1b  = (const float*)d_in[8];
    const float* t2    = (const float*)d_in[9];
    const float* b2    = (const float*)d_in[10];
    const float* A1_2  = (const float*)d_in[11];
    const float* A2_2  = (const float*)d_in[12];
    const float* be2a  = (const float*)d_in[13];
    const float* be2b  = (const float*)d_in[14];
    const float* t3    = (const float*)d_in[15];
    const float* b3    = (const float*)d_in[16];
    const float* A1_3  = (const float*)d_in[17];
    const float* A2_3  = (const float*)d_in[18];
    const float* be3a  = (const float*)d_in[19];
    const float* be3b  = (const float*)d_in[20];
    const float* A4    = (const float*)d_in[21];
    const float* beta4 = (const float*)d_in[22];

    float* ws  = (float*)d_ws;          // 6*T floats: softmaxed A vectors
    float* rws = ws + 6 * T;            // 3*64 floats: per-branch wb2

    k_softmax6<<<6, 256, 0, stream>>>(A1_1, A2_1, A1_2, A2_2, A1_3, A2_3, ws);

    k_branch_all<<<192, 256, 0, stream>>>(
        x1, x2, x3,
        t1, b1, be1a, be1b,
        t2, b2, be2a, be2b,
        t3, b3, be3a, be3b,
        ws, rws);

    k_final<<<1, 64, 0, stream>>>(A4, beta4, rws, (float*)d_out);
}

// Round 3
// 111.731 us; speedup vs baseline: 1.1361x; 1.1329x over previous
//
#include <hip/hip_runtime.h>
#include <math.h>

#define T 1024
#define NB 64

__device__ __forceinline__ float clip01(float v) {
    return fminf(fmaxf(v, 0.0f), 1.0f);
}

__device__ __forceinline__ float wave_reduce_sum(float v) {
    #pragma unroll
    for (int off = 32; off > 0; off >>= 1) v += __shfl_xor(v, off, 64);
    return v;
}

__device__ __forceinline__ float2 wave_reduce_max2(float2 v) {
    #pragma unroll
    for (int off = 32; off > 0; off >>= 1) {
        v.x = fmaxf(v.x, __shfl_xor(v.x, off, 64));
        v.y = fmaxf(v.y, __shfl_xor(v.y, off, 64));
    }
    return v;
}

__device__ __forceinline__ float2 wave_reduce_sum2(float2 v) {
    #pragma unroll
    for (int off = 32; off > 0; off >>= 1) {
        v.x += __shfl_xor(v.x, off, 64);
        v.y += __shfl_xor(v.y, off, 64);
    }
    return v;
}

// ---------------------------------------------------------------------------
// Fused branch kernel: one block per (branch, batch) = 192 blocks x 256 thr.
// Each block:
//   1. loads its branch's A1, A2 rows and softmaxes BOTH locally (redundant
//      across the 64 batch-blocks of a branch, but ~free: 8 expf/thread),
//      A1sm -> LDS (read later via uniform-address broadcast), A2sm -> regs.
//   2. builds S_ext[2T] in LDS (sigmoid of b - x*t with exact r==b -> -10).
//   3. sliding-register-window correlation, 4 rows/thread, 16 FMA/iter.
//   4. clip + A2-weighted shuffle reduction -> rws[br*NB + batch].
// ---------------------------------------------------------------------------
__global__ __launch_bounds__(256, 1) void k_branch_fused(
    const float* __restrict__ x1, const float* __restrict__ x2,
    const float* __restrict__ x3,
    const float* __restrict__ t1p, const float* __restrict__ b1p,
    const float* __restrict__ A1_1, const float* __restrict__ A2_1,
    const float* __restrict__ ba1, const float* __restrict__ bb1,
    const float* __restrict__ t2p, const float* __restrict__ b2p,
    const float* __restrict__ A1_2, const float* __restrict__ A2_2,
    const float* __restrict__ ba2, const float* __restrict__ bb2,
    const float* __restrict__ t3p, const float* __restrict__ b3p,
    const float* __restrict__ A1_3, const float* __restrict__ A2_3,
    const float* __restrict__ ba3, const float* __restrict__ bb3,
    float* __restrict__ rws)
{
    __shared__ float sS[2 * T];    // 8 KB: sigmoid row extended with sig(-10)
    __shared__ float sA1[T];       // 4 KB: softmaxed A1
    __shared__ float pr0[4], pr1[4];

    const int br    = blockIdx.x >> 6;   // 0..2
    const int batch = blockIdx.x & 63;   // 0..63
    const int tid   = threadIdx.x;
    const int wave  = tid >> 6;
    const int lane  = tid & 63;

    const float *x, *tp, *bp, *a1p, *a2p, *bap, *bbp;
    if (br == 0)      { x = x1; tp = t1p; bp = b1p; a1p = A1_1; a2p = A2_1; bap = ba1; bbp = bb1; }
    else if (br == 1) { x = x2; tp = t2p; bp = b2p; a1p = A1_2; a2p = A2_2; bap = ba2; bbp = bb2; }
    else              { x = x3; tp = t3p; bp = b3p; a1p = A1_3; a2p = A2_3; bap = ba3; bbp = bb3; }

    // Issue all global loads up front.
    const float4 xv  = ((const float4*)(x + (size_t)batch * T))[tid];
    const float4 a1r = ((const float4*)a1p)[tid];
    const float4 a2r = ((const float4*)a2p)[tid];
    const float tt = *tp;
    const float bb = *bp;
    const float beta_a = *bap;
    const float beta_b = *bbp;
    const float sig10 = 1.0f / (1.0f + expf(10.0f));   // sigmoid(-10)

    // --- dual softmax (A1 and A2 together) ---
    float2 mx = make_float2(fmaxf(fmaxf(a1r.x, a1r.y), fmaxf(a1r.z, a1r.w)),
                            fmaxf(fmaxf(a2r.x, a2r.y), fmaxf(a2r.z, a2r.w)));
    mx = wave_reduce_max2(mx);
    if (lane == 0) { pr0[wave] = mx.x; pr1[wave] = mx.y; }
    __syncthreads();
    const float m1 = fmaxf(fmaxf(pr0[0], pr0[1]), fmaxf(pr0[2], pr0[3]));
    const float m2 = fmaxf(fmaxf(pr1[0], pr1[1]), fmaxf(pr1[2], pr1[3]));

    float e10 = expf(a1r.x - m1), e11 = expf(a1r.y - m1);
    float e12 = expf(a1r.z - m1), e13 = expf(a1r.w - m1);
    float e20 = expf(a2r.x - m2), e21 = expf(a2r.y - m2);
    float e22 = expf(a2r.z - m2), e23 = expf(a2r.w - m2);
    float2 sm = make_float2((e10 + e11) + (e12 + e13),
                            (e20 + e21) + (e22 + e23));
    sm = wave_reduce_sum2(sm);
    __syncthreads();                 // pr0/pr1 reuse
    if (lane == 0) { pr0[wave] = sm.x; pr1[wave] = sm.y; }

    // --- sigmoid row (exact mul/sub semantics for the r==b test) ---
    float4 sv;
    {
        float p, r;
        p = __fmul_rn(xv.x, tt); r = __fsub_rn(bb, p); if (r == bb) r = -10.0f;
        sv.x = 1.0f / (1.0f + expf(-r));
        p = __fmul_rn(xv.y, tt); r = __fsub_rn(bb, p); if (r == bb) r = -10.0f;
        sv.y = 1.0f / (1.0f + expf(-r));
        p = __fmul_rn(xv.z, tt); r = __fsub_rn(bb, p); if (r == bb) r = -10.0f;
        sv.z = 1.0f / (1.0f + expf(-r));
        p = __fmul_rn(xv.w, tt); r = __fsub_rn(bb, p); if (r == bb) r = -10.0f;
        sv.w = 1.0f / (1.0f + expf(-r));
    }
    ((float4*)sS)[tid] = sv;
    ((float4*)(sS + T))[tid] = make_float4(sig10, sig10, sig10, sig10);
    __syncthreads();
    const float inv1 = 1.0f / ((pr0[0] + pr0[1]) + (pr0[2] + pr0[3]));
    const float inv2 = 1.0f / ((pr1[0] + pr1[1]) + (pr1[2] + pr1[3]));
    ((float4*)sA1)[tid] = make_float4(e10 * inv1, e11 * inv1, e12 * inv1, e13 * inv1);
    const float4 a2 = make_float4(e20 * inv2, e21 * inv2, e22 * inv2, e23 * inv2);
    __syncthreads();

    // --- correlation: rows 4*tid..4*tid+3, sliding register window ---
    float acc0 = 0.0f, acc1 = 0.0f, acc2 = 0.0f, acc3 = 0.0f;
    float4 u = ((const float4*)sS)[tid];
    #pragma unroll 8
    for (int jv = 0; jv < T / 4; ++jv) {
        const float4 a = ((const float4*)sA1)[jv];        // uniform -> broadcast
        const float4 v = ((const float4*)sS)[tid + jv + 1];
        acc0 = fmaf(a.x, u.x, acc0); acc0 = fmaf(a.y, u.y, acc0);
        acc0 = fmaf(a.z, u.z, acc0); acc0 = fmaf(a.w, u.w, acc0);
        acc1 = fmaf(a.x, u.y, acc1); acc1 = fmaf(a.y, u.z, acc1);
        acc1 = fmaf(a.z, u.w, acc1); acc1 = fmaf(a.w, v.x, acc1);
        acc2 = fmaf(a.x, u.z, acc2); acc2 = fmaf(a.y, u.w, acc2);
        acc2 = fmaf(a.z, v.x, acc2); acc2 = fmaf(a.w, v.y, acc2);
        acc3 = fmaf(a.x, u.w, acc3); acc3 = fmaf(a.y, v.x, acc3);
        acc3 = fmaf(a.z, v.y, acc3); acc3 = fmaf(a.w, v.z, acc3);
        u = v;
    }

    // --- epilogue ---
    float act0 = clip01(1.0f - beta_a + acc0);
    float act1 = clip01(1.0f - beta_a + acc1);
    float act2 = clip01(1.0f - beta_a + acc2);
    float act3 = clip01(1.0f - beta_a + acc3);

    float part = a2.x * (1.0f - act0) + a2.y * (1.0f - act1)
               + a2.z * (1.0f - act2) + a2.w * (1.0f - act3);
    part = wave_reduce_sum(part);
    __syncthreads();                 // pr0 reuse
    if (lane == 0) pr0[wave] = part;
    __syncthreads();
    if (tid == 0) {
        float tot = (pr0[0] + pr0[1]) + (pr0[2] + pr0[3]);
        rws[br * NB + batch] = clip01(beta_b - tot);
    }
}

// ---------------------------------------------------------------------------
// Final 3-way softmax combine. 1 block x 64 threads.
// ---------------------------------------------------------------------------
__global__ __launch_bounds__(64) void k_final(
    const float* __restrict__ A4, const float* __restrict__ beta4p,
    const float* __restrict__ rws, float* __restrict__ out)
{
    int b = threadIdx.x;
    float a0 = A4[0], a1 = A4[1], a2 = A4[2];
    float m = fmaxf(a0, fmaxf(a1, a2));
    float e0 = expf(a0 - m), e1 = expf(a1 - m), e2 = expf(a2 - m);
    float inv = 1.0f / ((e0 + e1) + e2);
    float beta4 = *beta4p;
    float r0 = rws[0 * NB + b];
    float r1 = rws[1 * NB + b];
    float r2 = rws[2 * NB + b];
    float wb4 = beta4 - (e0 * inv * (1.0f - r0)
                       + e1 * inv * (1.0f - r1)
                       + e2 * inv * (1.0f - r2));
    out[b] = clip01(wb4);
}

extern "C" void kernel_launch(void* const* d_in, const int* in_sizes, int n_in,
                              void* d_out, int out_size, void* d_ws, size_t ws_size,
                              hipStream_t stream) {
    const float* x1    = (const float*)d_in[0];
    const float* x2    = (const float*)d_in[1];
    const float* x3    = (const float*)d_in[2];
    const float* t1    = (const float*)d_in[3];
    const float* b1    = (const float*)d_in[4];
    const float* A1_1  = (const float*)d_in[5];
    const float* A2_1  = (const float*)d_in[6];
    const float* be1a  = (const float*)d_in[7];
    const float* be1b  = (const float*)d_in[8];
    const float* t2    = (const float*)d_in[9];
    const float* b2    = (const float*)d_in[10];
    const float* A1_2  = (const float*)d_in[11];
    const float* A2_2  = (const float*)d_in[12];
    const float* be2a  = (const float*)d_in[13];
    const float* be2b  = (const float*)d_in[14];
    const float* t3    = (const float*)d_in[15];
    const float* b3    = (const float*)d_in[16];
    const float* A1_3  = (const float*)d_in[17];
    const float* A2_3  = (const float*)d_in[18];
    const float* be3a  = (const float*)d_in[19];
    const float* be3b  = (const float*)d_in[20];
    const float* A4    = (const float*)d_in[21];
    const float* beta4 = (const float*)d_in[22];

    float* rws = (float*)d_ws;          // 3*64 floats: per-branch wb2

    k_branch_fused<<<192, 256, 0, stream>>>(
        x1, x2, x3,
        t1, b1, A1_1, A2_1, be1a, be1b,
        t2, b2, A1_2, A2_2, be2a, be2b,
        t3, b3, A1_3, A2_3, be3a, be3b,
        rws);

    k_final<<<1, 64, 0, stream>>>(A4, beta4, rws, (float*)d_out);
}